// Round 13
// baseline (64.981 us; speedup 1.0000x reference)
//
#include <hip/hip_runtime.h>

#define A_DIM 1024
#define B_DIM 1024

typedef __attribute__((ext_vector_type(8))) short bfrag8;
typedef __attribute__((ext_vector_type(4))) float facc4;

__device__ __forceinline__ unsigned short f2bf(float f) {
    unsigned u = __float_as_uint(f);
    u = (u + 0x7FFFu + ((u >> 16) & 1u)) >> 16;
    return (unsigned short)u;
}
__device__ __forceinline__ unsigned cvtpk(float lo, float hi) {
    unsigned r;
    asm("v_cvt_pk_bf16_f32 %0, %1, %2" : "=v"(r) : "v"(lo), "v"(hi));
    return r;
}

// ---------------------------------------------------------------------------
// Kernel 1: fused prep + edge MLP via MFMA. R12's verified 2-deep
// register-pinned asm pipeline (56-64 VGPR, no spill), extended to 16
// rows/wave: grid (16 bg, 16 at) = 256 blocks = exactly 1/CU (8 XCDs x 32
// round-robin, perfectly balanced). Prologue (prep + drain + fill) now runs
// once per 64 a-rows. Counted s_waitcnt vmcnt = {4, 7 x14, 3}; steady-state
// 7 is hardware-verified in R10 and R12 (4 asm loads/stage, 3 asm
// stores/step, in-order retirement). sched_barrier(0) after every wait.
// Wave w: b-half mh=w&1 (mt tiles 2mh,2mh+1), rows r0 = at*64+(w>>1)*16.
// C/D layout: col = lane&15 (edge), row = (lane>>4)*4 + reg.
// ---------------------------------------------------------------------------
__global__ __launch_bounds__(512, 4) void edge_kernel(
    const float* __restrict__ E, const float* __restrict__ na,
    const float* __restrict__ nb, const float* __restrict__ W1e,
    const float* __restrict__ b1e, const float* __restrict__ W2e,
    const float* __restrict__ b2e, float* __restrict__ el_out,
    float* __restrict__ suma_p, float* __restrict__ sumb_p)
{
    __shared__ __align__(16) float sb[5120];          // 20 KB: prep stage / combine
    __shared__ __align__(16) float ha_s[64 * 16];     // 4 KB
    __shared__ __align__(16) float hb_s[64 * 16];     // 4 KB

    const int tid  = threadIdx.x;
    const int lane = tid & 63;
    const int w    = tid >> 6;          // 0..7
    const int n    = lane & 15;
    const int g    = lane >> 4;
    const int bg   = blockIdx.x;        // 0..15
    const int at   = blockIdx.y;        // 0..15
    const int bbase = bg * 64;
    const int abase = at * 64;
    const int mh   = w & 1;
    const int rg   = w >> 1;            // 0..3
    const int r0   = abase + rg * 16;
    const int mt0  = mh * 2, mt1 = mh * 2 + 1;

    float4 bufA[4], bufB[4];

#define LOADH(BUF, AROW)                                                       \
    {                                                                          \
        const float* p_  = E + ((size_t)(AROW) * B_DIM + bbase) * 32;          \
        const float* p0_ = p_ + (mt0 * 16 + n) * 32 + g * 8;                   \
        const float* p1_ = p_ + (mt1 * 16 + n) * 32 + g * 8;                   \
        asm volatile("global_load_dwordx4 %0, %1, off"                         \
                     : "=v"(BUF[0]) : "v"(p0_) : "memory");                    \
        asm volatile("global_load_dwordx4 %0, %1, off"                         \
                     : "=v"(BUF[1]) : "v"(p0_ + 4) : "memory");                \
        asm volatile("global_load_dwordx4 %0, %1, off"                         \
                     : "=v"(BUF[2]) : "v"(p1_) : "memory");                    \
        asm volatile("global_load_dwordx4 %0, %1, off"                         \
                     : "=v"(BUF[3]) : "v"(p1_ + 4) : "memory");                \
    }

    // ---- prep stage: na tile / nb tile / W1e[32..96) into LDS, coalesced ----
    float* xa_s = sb;                 // 64*32 f32 (8 KB)
    float* xb_s = sb + 2048;          // 64*32 f32 (8 KB)
    float* wq_s = sb + 4096;          // 64*16 f32 (4 KB, W1e rows 32..95)
    ((float4*)xa_s)[tid] = ((const float4*)(na + (size_t)abase * 32))[tid];
    ((float4*)xb_s)[tid] = ((const float4*)(nb + (size_t)bbase * 32))[tid];
    if (tid < 256)
        ((float4*)wq_s)[tid] = ((const float4*)(W1e + 32 * 16))[tid];

    // weight fragments (global, L1-hot; complete before the baseline drain)
    bfrag8 w1f, w2f;
    #pragma unroll
    for (int t = 0; t < 8; ++t) {
        w1f[t] = (short)f2bf(W1e[(g * 8 + t) * 16 + n]);
        w2f[t] = (g < 2) ? (short)f2bf(W2e[(g * 8 + t) * 16 + n]) : (short)0;
    }
    facc4 b2f = *(const facc4*)&b2e[g * 4];
    __syncthreads();

    // ---- prep compute: all operands LDS-broadcast (2 rows/thread/side) ----
    {
        const int r = tid >> 4, d = tid & 15;   // r 0..31
        float aa0 = b1e[d], aa1 = aa0;
        float ab0 = 0.f, ab1 = 0.f;
        #pragma unroll
        for (int k = 0; k < 32; ++k) {
            float wa = wq_s[k * 16 + d];
            aa0 += xa_s[r * 32 + k] * wa;
            aa1 += xa_s[(r + 32) * 32 + k] * wa;
            float wv = wq_s[(32 + k) * 16 + d];
            ab0 += xb_s[r * 32 + k] * wv;
            ab1 += xb_s[(r + 32) * 32 + k] * wv;
        }
        ha_s[r * 16 + d] = aa0;
        ha_s[(r + 32) * 16 + d] = aa1;
        hb_s[r * 16 + d] = ab0;
        hb_s[(r + 32) * 16 + d] = ab1;
    }
    __syncthreads();

    facc4 hbF0 = *(const facc4*)&hb_s[(mt0 * 16 + n) * 16 + g * 4];
    facc4 hbF1 = *(const facc4*)&hb_s[(mt1 * 16 + n) * 16 + g * 4];
    facc4 sumb0 = facc4{0.f, 0.f, 0.f, 0.f};
    facc4 sumb1 = facc4{0.f, 0.f, 0.f, 0.f};

#define PVTILE(V0, V1, MT, HBF, SUMB, AROW, HAF)                               \
    {                                                                          \
        union { unsigned u[4]; bfrag8 s; } ef_;                                \
        ef_.u[0] = cvtpk((V0).x, (V0).y); ef_.u[1] = cvtpk((V0).z, (V0).w);    \
        ef_.u[2] = cvtpk((V1).x, (V1).y); ef_.u[3] = cvtpk((V1).z, (V1).w);    \
        facc4 h_ = __builtin_amdgcn_mfma_f32_16x16x32_bf16(                    \
            w1f, ef_.s, (HAF) + (HBF), 0, 0, 0);                               \
        h_.x = fmaxf(h_.x, 0.f); h_.y = fmaxf(h_.y, 0.f);                      \
        h_.z = fmaxf(h_.z, 0.f); h_.w = fmaxf(h_.w, 0.f);                      \
        const int sl_ = (n + g * 32) & 63;                                     \
        const int sh_ = (n + g * 32 + 16) & 63;                                \
        float v0_ = __shfl(h_.x, sl_), v1_ = __shfl(h_.y, sl_);                \
        float v2_ = __shfl(h_.z, sl_), v3_ = __shfl(h_.w, sl_);                \
        float u0_ = __shfl(h_.x, sh_), u1_ = __shfl(h_.y, sh_);                \
        float u2_ = __shfl(h_.z, sh_), u3_ = __shfl(h_.w, sh_);                \
        union { unsigned u[4]; bfrag8 s; } bb_;                                \
        bb_.u[0] = cvtpk(v0_, v1_); bb_.u[1] = cvtpk(v2_, v3_);                \
        bb_.u[2] = cvtpk(u0_, u1_); bb_.u[3] = cvtpk(u2_, u3_);                \
        facc4 e_ = __builtin_amdgcn_mfma_f32_16x16x32_bf16(                    \
            w2f, bb_.s, b2f, 0, 0, 0);                                         \
        e_.x = fmaxf(e_.x, 0.f); e_.y = fmaxf(e_.y, 0.f);                      \
        e_.z = fmaxf(e_.z, 0.f); e_.w = fmaxf(e_.w, 0.f);                      \
        float* op_ = &el_out[((size_t)(AROW) * B_DIM + bbase + (MT) * 16 + n)  \
                             * 16 + g * 4];                                    \
        asm volatile("global_store_dwordx4 %0, %1, off"                        \
                     :: "v"(op_), "v"(e_) : "memory");                         \
        SUMB += e_;                                                            \
        ssum += e_;                                                            \
    }

#define COMPUTE(BUF, AROW, S)                                                  \
    {                                                                          \
        facc4 haf_ = *(const facc4*)&ha_s[(rg * 16 + (S)) * 16 + g * 4];       \
        facc4 ssum = facc4{0.f, 0.f, 0.f, 0.f};                                \
        PVTILE(BUF[0], BUF[1], mt0, hbF0, sumb0, AROW, haf_)                   \
        PVTILE(BUF[2], BUF[3], mt1, hbF1, sumb1, AROW, haf_)                   \
        _Pragma("unroll")                                                      \
        for (int m_ = 1; m_ <= 8; m_ <<= 1) {                                  \
            ssum.x += __shfl_xor(ssum.x, m_);                                  \
            ssum.y += __shfl_xor(ssum.y, m_);                                  \
            ssum.z += __shfl_xor(ssum.z, m_);                                  \
            ssum.w += __shfl_xor(ssum.w, m_);                                  \
        }                                                                      \
        if (n == 0) {                                                          \
            float* sp_ = &suma_p[((size_t)(bg * 2 + mh) * A_DIM + (AROW)) * 16 \
                                 + g * 4];                                     \
            asm volatile("global_store_dwordx4 %0, %1, off"                    \
                         :: "v"(sp_), "v"(ssum) : "memory");                   \
        }                                                                      \
    }

#define WAITV(N)                                                               \
    asm volatile("s_waitcnt vmcnt(" #N ")" ::: "memory");                      \
    __builtin_amdgcn_sched_barrier(0);

    // baseline: no prep vmem outstanding -> counts below are exact
    WAITV(0)

    // 2-deep pinned pipeline, 16 steps (steady-state count 7, HW-verified):
    LOADH(bufA, r0)
    LOADH(bufB, r0 + 1)
    WAITV(4)
    COMPUTE(bufA, r0, 0)
    LOADH(bufA, r0 + 2)
    WAITV(7)
    COMPUTE(bufB, r0 + 1, 1)
    LOADH(bufB, r0 + 3)
    WAITV(7)
    COMPUTE(bufA, r0 + 2, 2)
    LOADH(bufA, r0 + 4)
    WAITV(7)
    COMPUTE(bufB, r0 + 3, 3)
    LOADH(bufB, r0 + 5)
    WAITV(7)
    COMPUTE(bufA, r0 + 4, 4)
    LOADH(bufA, r0 + 6)
    WAITV(7)
    COMPUTE(bufB, r0 + 5, 5)
    LOADH(bufB, r0 + 7)
    WAITV(7)
    COMPUTE(bufA, r0 + 6, 6)
    LOADH(bufA, r0 + 8)
    WAITV(7)
    COMPUTE(bufB, r0 + 7, 7)
    LOADH(bufB, r0 + 9)
    WAITV(7)
    COMPUTE(bufA, r0 + 8, 8)
    LOADH(bufA, r0 + 10)
    WAITV(7)
    COMPUTE(bufB, r0 + 9, 9)
    LOADH(bufB, r0 + 11)
    WAITV(7)
    COMPUTE(bufA, r0 + 10, 10)
    LOADH(bufA, r0 + 12)
    WAITV(7)
    COMPUTE(bufB, r0 + 11, 11)
    LOADH(bufB, r0 + 13)
    WAITV(7)
    COMPUTE(bufA, r0 + 12, 12)
    LOADH(bufA, r0 + 14)
    WAITV(7)
    COMPUTE(bufB, r0 + 13, 13)
    LOADH(bufB, r0 + 15)
    WAITV(7)
    COMPUTE(bufA, r0 + 14, 14)
    WAITV(3)
    COMPUTE(bufB, r0 + 15, 15)

#undef LOADH
#undef PVTILE
#undef COMPUTE
#undef WAITV

    // ---- sumb combine across the 4 waves sharing each b-half ----
    __syncthreads();
    *(facc4*)&sb[((w * 32 + n) * 4 + g) * 4]      = sumb0;
    *(facc4*)&sb[((w * 32 + 16 + n) * 4 + g) * 4] = sumb1;
    __syncthreads();
    if (tid < 256) {
        const int b = tid >> 2, q = tid & 3;
        const int mh2 = b >> 5, rest = b & 31;
        facc4 s = facc4{0.f, 0.f, 0.f, 0.f};
        #pragma unroll
        for (int rg2 = 0; rg2 < 4; ++rg2)
            s += *(const facc4*)&sb[(((rg2 * 2 + mh2) * 32 + rest) * 4 + q) * 4];
        *(facc4*)&sumb_p[((size_t)at * B_DIM + bbase + b) * 16 + q * 4] = s;
    }
}

// ---------------------------------------------------------------------------
// Kernel 2: node MLP for both sides, inlined partial reduction.
// a-side: 32 partials (bg x mh, split 2x16); b-side: 16 partials (at, 2x8).
// ---------------------------------------------------------------------------
__global__ __launch_bounds__(256) void node_kernel(
    const float* __restrict__ na, const float* __restrict__ nb,
    const float* __restrict__ suma_p, const float* __restrict__ sumb_p,
    const float* __restrict__ W1n, const float* __restrict__ b1n,
    const float* __restrict__ W2n, const float* __restrict__ b2n,
    float* __restrict__ out_a, float* __restrict__ out_b)
{
    __shared__ float W1_s[48 * 32];
    __shared__ float W2_s[32 * 32];
    __shared__ float hid_s[8][32];
    __shared__ float sx2[8][32];
    __shared__ float sx_s[8][16];
    int tid = threadIdx.x;
    for (int i = tid; i < 1536; i += 256) W1_s[i] = W1n[i];
    for (int i = tid; i < 1024; i += 256) W2_s[i] = W2n[i];
    int rlocal = tid >> 5;
    int r = blockIdx.x * 8 + rlocal;
    int j = tid & 31;
    int isb = (r >= 1024);
    int rr = isb ? r - 1024 : r;
    {
        const float* P = isb ? sumb_p : suma_p;
        int hn = isb ? 8 : 16;
        int d = j & 15, hf = j >> 4;
        float acc = 0.f;
        for (int t = hf * hn; t < hf * hn + hn; ++t)
            acc += P[(size_t)t * 16384 + rr * 16 + d];
        sx2[rlocal][j] = acc;
    }
    __syncthreads();
    if (j < 16) sx_s[rlocal][j] = sx2[rlocal][j] + sx2[rlocal][j + 16];
    __syncthreads();
    const float* nx = (isb ? nb : na) + rr * 32;
    float acc = b1n[j];
    #pragma unroll
    for (int k = 0; k < 32; ++k) acc += nx[k] * W1_s[k * 32 + j];
    #pragma unroll
    for (int k = 0; k < 16; ++k) acc += sx_s[rlocal][k] * W1_s[(32 + k) * 32 + j];
    hid_s[rlocal][j] = fmaxf(acc, 0.f);
    __syncthreads();
    float acc2 = b2n[j];
    #pragma unroll
    for (int k = 0; k < 32; ++k) acc2 += hid_s[rlocal][k] * W2_s[k * 32 + j];
    (isb ? out_b : out_a)[rr * 32 + j] = fmaxf(acc2, 0.f);
}

extern "C" void kernel_launch(void* const* d_in, const int* in_sizes, int n_in,
                              void* d_out, int out_size, void* d_ws, size_t ws_size,
                              hipStream_t stream)
{
    const float* E   = (const float*)d_in[0];
    const float* na  = (const float*)d_in[1];
    const float* nb  = (const float*)d_in[2];
    const float* W1e = (const float*)d_in[3];
    const float* b1e = (const float*)d_in[4];
    const float* W2e = (const float*)d_in[5];
    const float* b2e = (const float*)d_in[6];
    const float* W1n = (const float*)d_in[7];
    const float* b1n = (const float*)d_in[8];
    const float* W2n = (const float*)d_in[9];
    const float* b2n = (const float*)d_in[10];

    float* out    = (float*)d_out;
    float* el_out = out;
    float* out_a  = out + (size_t)A_DIM * B_DIM * 16;
    float* out_b  = out_a + A_DIM * 32;

    float* ws     = (float*)d_ws;
    float* suma_p = ws;                      // 32 * 16384
    float* sumb_p = ws + 32 * 16384;         // 16 * 16384

    hipLaunchKernelGGL(edge_kernel, dim3(16, 16), dim3(512), 0, stream,
                       E, na, nb, W1e, b1e, W2e, b2e, el_out, suma_p, sumb_p);
    hipLaunchKernelGGL(node_kernel, dim3(256), dim3(256), 0, stream,
                       na, nb, suma_p, sumb_p, W1n, b1n, W2n, b2n, out_a, out_b);
}

// Round 14
// 47.439 us; speedup vs baseline: 1.3698x; 1.3698x over previous
//
#include <hip/hip_runtime.h>

#define A_DIM 1024
#define B_DIM 1024

typedef __attribute__((ext_vector_type(8))) short bfrag8;
typedef __attribute__((ext_vector_type(4))) float facc4;

__device__ __forceinline__ unsigned short f2bf(float f) {
    unsigned u = __float_as_uint(f);
    u = (u + 0x7FFFu + ((u >> 16) & 1u)) >> 16;
    return (unsigned short)u;
}
__device__ __forceinline__ unsigned cvtpk(float lo, float hi) {
    unsigned r;
    asm("v_cvt_pk_bf16_f32 %0, %1, %2" : "=v"(r) : "v"(lo), "v"(hi));
    return r;
}

// ---------------------------------------------------------------------------
// Kernel 1: fused prep + edge MLP via MFMA. EXACT R12 structure (best, 47.3us:
// 2-deep register-pinned asm pipeline, 8 rows/wave, grid (16,32) = 512 blocks
// = 2 blocks/CU = 16 waves/CU -- R13 proved 1 block/CU regresses), plus
// prologue/pipeline overlap: the first two pinned LOADH stages are issued
// BEFORE prep. Compiler prep waitcnts are conservative-safe (my asm loads
// precede all compiler loads in program order, so any compiler vmcnt(k)
// over-waits). The prep __syncthreads drains vmcnt(0), so bufA/bufB retire
// for free under prep's compute, steps 0/1 need no wait, and the baseline
// WAITV(0) disappears. Steady-state vmcnt(7) / tail (3) are the R10/R12
// hardware-verified counts (4 asm loads/stage, 3 asm stores/step, in-order).
// sched_barrier(0) after every wait (rule #18).
// Wave w: b-half mh=w&1 (mt tiles 2mh,2mh+1), rows r0 = at*32+(w>>1)*8..+7.
// C/D layout: col = lane&15 (edge), row = (lane>>4)*4 + reg.
// ---------------------------------------------------------------------------
__global__ __launch_bounds__(512, 4) void edge_kernel(
    const float* __restrict__ E, const float* __restrict__ na,
    const float* __restrict__ nb, const float* __restrict__ W1e,
    const float* __restrict__ b1e, const float* __restrict__ W2e,
    const float* __restrict__ b2e, float* __restrict__ el_out,
    float* __restrict__ suma_p, float* __restrict__ sumb_p)
{
    __shared__ __align__(16) float sb[4096];          // 16 KB: prep stage / combine
    __shared__ __align__(16) float ha_s[32 * 16];     // 2 KB
    __shared__ __align__(16) float hb_s[64 * 16];     // 4 KB

    const int tid  = threadIdx.x;
    const int lane = tid & 63;
    const int w    = tid >> 6;          // 0..7
    const int n    = lane & 15;
    const int g    = lane >> 4;
    const int bg   = blockIdx.x;        // 0..15
    const int at   = blockIdx.y;        // 0..31
    const int bbase = bg * 64;
    const int abase = at * 32;
    const int mh   = w & 1;
    const int rg   = w >> 1;            // 0..3
    const int r0   = abase + rg * 8;
    const int mt0  = mh * 2, mt1 = mh * 2 + 1;

    float4 bufA[4], bufB[4];

#define LOADH(BUF, AROW)                                                       \
    {                                                                          \
        const float* p_  = E + ((size_t)(AROW) * B_DIM + bbase) * 32;          \
        const float* p0_ = p_ + (mt0 * 16 + n) * 32 + g * 8;                   \
        const float* p1_ = p_ + (mt1 * 16 + n) * 32 + g * 8;                   \
        asm volatile("global_load_dwordx4 %0, %1, off"                         \
                     : "=v"(BUF[0]) : "v"(p0_) : "memory");                    \
        asm volatile("global_load_dwordx4 %0, %1, off"                         \
                     : "=v"(BUF[1]) : "v"(p0_ + 4) : "memory");                \
        asm volatile("global_load_dwordx4 %0, %1, off"                         \
                     : "=v"(BUF[2]) : "v"(p1_) : "memory");                    \
        asm volatile("global_load_dwordx4 %0, %1, off"                         \
                     : "=v"(BUF[3]) : "v"(p1_ + 4) : "memory");                \
    }

    // ---- pipeline fill ISSUED FIRST: latency hides under the whole prep ----
    LOADH(bufA, r0)
    LOADH(bufB, r0 + 1)

    // ---- prep stage: na tile / nb tile / W1e[32..96) into LDS, coalesced ----
    float* xa_s = sb;                 // 32*32 f32
    float* xb_s = sb + 1024;          // 64*32 f32
    float* wq_s = sb + 1024 + 2048;   // 64*16 f32  (W1e rows 32..95)
    if (tid < 256)
        ((float4*)xa_s)[tid] = ((const float4*)(na + (size_t)abase * 32))[tid];
    ((float4*)xb_s)[tid] = ((const float4*)(nb + (size_t)bbase * 32))[tid];
    if (tid < 256)
        ((float4*)wq_s)[tid] = ((const float4*)(W1e + 32 * 16))[tid];

    // weight fragments (global, L1-hot)
    bfrag8 w1f, w2f;
    #pragma unroll
    for (int t = 0; t < 8; ++t) {
        w1f[t] = (short)f2bf(W1e[(g * 8 + t) * 16 + n]);
        w2f[t] = (g < 2) ? (short)f2bf(W2e[(g * 8 + t) * 16 + n]) : (short)0;
    }
    facc4 b2f = *(const facc4*)&b2e[g * 4];
    __syncthreads();

    // ---- prep compute: all operands LDS-broadcast ----
    {
        const int r = tid >> 4, d = tid & 15;   // r 0..31
        float acca = b1e[d];
        #pragma unroll
        for (int k = 0; k < 32; ++k)
            acca += xa_s[r * 32 + k] * wq_s[k * 16 + d];
        ha_s[r * 16 + d] = acca;
        float ab0 = 0.f, ab1 = 0.f;
        #pragma unroll
        for (int k = 0; k < 32; ++k) {
            float wv = wq_s[(32 + k) * 16 + d];
            ab0 += xb_s[r * 32 + k] * wv;
            ab1 += xb_s[(r + 32) * 32 + k] * wv;
        }
        hb_s[r * 16 + d] = ab0;
        hb_s[(r + 32) * 16 + d] = ab1;
    }
    __syncthreads();   // implicit vmcnt(0): bufA/bufB retired here, for free

    facc4 hbF0 = *(const facc4*)&hb_s[(mt0 * 16 + n) * 16 + g * 4];
    facc4 hbF1 = *(const facc4*)&hb_s[(mt1 * 16 + n) * 16 + g * 4];
    facc4 sumb0 = facc4{0.f, 0.f, 0.f, 0.f};
    facc4 sumb1 = facc4{0.f, 0.f, 0.f, 0.f};

#define PVTILE(V0, V1, MT, HBF, SUMB, AROW, HAF)                               \
    {                                                                          \
        union { unsigned u[4]; bfrag8 s; } ef_;                                \
        ef_.u[0] = cvtpk((V0).x, (V0).y); ef_.u[1] = cvtpk((V0).z, (V0).w);    \
        ef_.u[2] = cvtpk((V1).x, (V1).y); ef_.u[3] = cvtpk((V1).z, (V1).w);    \
        facc4 h_ = __builtin_amdgcn_mfma_f32_16x16x32_bf16(                    \
            w1f, ef_.s, (HAF) + (HBF), 0, 0, 0);                               \
        h_.x = fmaxf(h_.x, 0.f); h_.y = fmaxf(h_.y, 0.f);                      \
        h_.z = fmaxf(h_.z, 0.f); h_.w = fmaxf(h_.w, 0.f);                      \
        const int sl_ = (n + g * 32) & 63;                                     \
        const int sh_ = (n + g * 32 + 16) & 63;                                \
        float v0_ = __shfl(h_.x, sl_), v1_ = __shfl(h_.y, sl_);                \
        float v2_ = __shfl(h_.z, sl_), v3_ = __shfl(h_.w, sl_);                \
        float u0_ = __shfl(h_.x, sh_), u1_ = __shfl(h_.y, sh_);                \
        float u2_ = __shfl(h_.z, sh_), u3_ = __shfl(h_.w, sh_);                \
        union { unsigned u[4]; bfrag8 s; } bb_;                                \
        bb_.u[0] = cvtpk(v0_, v1_); bb_.u[1] = cvtpk(v2_, v3_);                \
        bb_.u[2] = cvtpk(u0_, u1_); bb_.u[3] = cvtpk(u2_, u3_);                \
        facc4 e_ = __builtin_amdgcn_mfma_f32_16x16x32_bf16(                    \
            w2f, bb_.s, b2f, 0, 0, 0);                                         \
        e_.x = fmaxf(e_.x, 0.f); e_.y = fmaxf(e_.y, 0.f);                      \
        e_.z = fmaxf(e_.z, 0.f); e_.w = fmaxf(e_.w, 0.f);                      \
        float* op_ = &el_out[((size_t)(AROW) * B_DIM + bbase + (MT) * 16 + n)  \
                             * 16 + g * 4];                                    \
        asm volatile("global_store_dwordx4 %0, %1, off"                        \
                     :: "v"(op_), "v"(e_) : "memory");                         \
        SUMB += e_;                                                            \
        ssum += e_;                                                            \
    }

#define COMPUTE(BUF, AROW, S)                                                  \
    {                                                                          \
        facc4 haf_ = *(const facc4*)&ha_s[(rg * 8 + (S)) * 16 + g * 4];        \
        facc4 ssum = facc4{0.f, 0.f, 0.f, 0.f};                                \
        PVTILE(BUF[0], BUF[1], mt0, hbF0, sumb0, AROW, haf_)                   \
        PVTILE(BUF[2], BUF[3], mt1, hbF1, sumb1, AROW, haf_)                   \
        _Pragma("unroll")                                                      \
        for (int m_ = 1; m_ <= 8; m_ <<= 1) {                                  \
            ssum.x += __shfl_xor(ssum.x, m_);                                  \
            ssum.y += __shfl_xor(ssum.y, m_);                                  \
            ssum.z += __shfl_xor(ssum.z, m_);                                  \
            ssum.w += __shfl_xor(ssum.w, m_);                                  \
        }                                                                      \
        if (n == 0) {                                                          \
            float* sp_ = &suma_p[((size_t)(bg * 2 + mh) * A_DIM + (AROW)) * 16 \
                                 + g * 4];                                     \
            asm volatile("global_store_dwordx4 %0, %1, off"                    \
                         :: "v"(sp_), "v"(ssum) : "memory");                   \
        }                                                                      \
    }

#define WAITV(N)                                                               \
    asm volatile("s_waitcnt vmcnt(" #N ")" ::: "memory");                      \
    __builtin_amdgcn_sched_barrier(0);

    // 2-deep pinned pipeline, 8 steps. Queue math after the barrier drain
    // (q=0; 4 loads/stage, 3 stores/step):
    // C0 LA | C1 LB |7| C2 LA |7| C3 LB |7| C4 LA |7| C5 LB |7| C6 |3| C7
    COMPUTE(bufA, r0, 0)
    LOADH(bufA, r0 + 2)
    COMPUTE(bufB, r0 + 1, 1)
    LOADH(bufB, r0 + 3)
    WAITV(7)
    COMPUTE(bufA, r0 + 2, 2)
    LOADH(bufA, r0 + 4)
    WAITV(7)
    COMPUTE(bufB, r0 + 3, 3)
    LOADH(bufB, r0 + 5)
    WAITV(7)
    COMPUTE(bufA, r0 + 4, 4)
    LOADH(bufA, r0 + 6)
    WAITV(7)
    COMPUTE(bufB, r0 + 5, 5)
    LOADH(bufB, r0 + 7)
    WAITV(7)
    COMPUTE(bufA, r0 + 6, 6)
    WAITV(3)
    COMPUTE(bufB, r0 + 7, 7)

#undef LOADH
#undef PVTILE
#undef COMPUTE
#undef WAITV

    // ---- sumb combine across the 4 waves sharing each b-half ----
    __syncthreads();
    *(facc4*)&sb[((w * 32 + n) * 4 + g) * 4]      = sumb0;
    *(facc4*)&sb[((w * 32 + 16 + n) * 4 + g) * 4] = sumb1;
    __syncthreads();
    if (tid < 256) {
        const int b = tid >> 2, q = tid & 3;
        const int mh2 = b >> 5, rest = b & 31;
        facc4 s = facc4{0.f, 0.f, 0.f, 0.f};
        #pragma unroll
        for (int rg2 = 0; rg2 < 4; ++rg2)
            s += *(const facc4*)&sb[(((rg2 * 2 + mh2) * 32 + rest) * 4 + q) * 4];
        *(facc4*)&sumb_p[((size_t)at * B_DIM + bbase + b) * 16 + q * 4] = s;
    }
}

// ---------------------------------------------------------------------------
// Kernel 2: node MLP for both sides, inlined partial reduction.
// Both sides have 32 partials (split 2x16 across lane halves).
// ---------------------------------------------------------------------------
__global__ __launch_bounds__(256) void node_kernel(
    const float* __restrict__ na, const float* __restrict__ nb,
    const float* __restrict__ suma_p, const float* __restrict__ sumb_p,
    const float* __restrict__ W1n, const float* __restrict__ b1n,
    const float* __restrict__ W2n, const float* __restrict__ b2n,
    float* __restrict__ out_a, float* __restrict__ out_b)
{
    __shared__ float W1_s[48 * 32];
    __shared__ float W2_s[32 * 32];
    __shared__ float hid_s[8][32];
    __shared__ float sx2[8][32];
    __shared__ float sx_s[8][16];
    int tid = threadIdx.x;
    for (int i = tid; i < 1536; i += 256) W1_s[i] = W1n[i];
    for (int i = tid; i < 1024; i += 256) W2_s[i] = W2n[i];
    int rlocal = tid >> 5;
    int r = blockIdx.x * 8 + rlocal;
    int j = tid & 31;
    int isb = (r >= 1024);
    int rr = isb ? r - 1024 : r;
    {
        const float* P = isb ? sumb_p : suma_p;
        int d = j & 15, hf = j >> 4;
        float acc = 0.f;
        #pragma unroll
        for (int t = hf * 16; t < hf * 16 + 16; ++t)
            acc += P[(size_t)t * 16384 + rr * 16 + d];
        sx2[rlocal][j] = acc;
    }
    __syncthreads();
    if (j < 16) sx_s[rlocal][j] = sx2[rlocal][j] + sx2[rlocal][j + 16];
    __syncthreads();
    const float* nx = (isb ? nb : na) + rr * 32;
    float acc = b1n[j];
    #pragma unroll
    for (int k = 0; k < 32; ++k) acc += nx[k] * W1_s[k * 32 + j];
    #pragma unroll
    for (int k = 0; k < 16; ++k) acc += sx_s[rlocal][k] * W1_s[(32 + k) * 32 + j];
    hid_s[rlocal][j] = fmaxf(acc, 0.f);
    __syncthreads();
    float acc2 = b2n[j];
    #pragma unroll
    for (int k = 0; k < 32; ++k) acc2 += hid_s[rlocal][k] * W2_s[k * 32 + j];
    (isb ? out_b : out_a)[rr * 32 + j] = fmaxf(acc2, 0.f);
}

extern "C" void kernel_launch(void* const* d_in, const int* in_sizes, int n_in,
                              void* d_out, int out_size, void* d_ws, size_t ws_size,
                              hipStream_t stream)
{
    const float* E   = (const float*)d_in[0];
    const float* na  = (const float*)d_in[1];
    const float* nb  = (const float*)d_in[2];
    const float* W1e = (const float*)d_in[3];
    const float* b1e = (const float*)d_in[4];
    const float* W2e = (const float*)d_in[5];
    const float* b2e = (const float*)d_in[6];
    const float* W1n = (const float*)d_in[7];
    const float* b1n = (const float*)d_in[8];
    const float* W2n = (const float*)d_in[9];
    const float* b2n = (const float*)d_in[10];

    float* out    = (float*)d_out;
    float* el_out = out;
    float* out_a  = out + (size_t)A_DIM * B_DIM * 16;
    float* out_b  = out_a + A_DIM * 32;

    float* ws     = (float*)d_ws;
    float* suma_p = ws;                      // 32 * 16384
    float* sumb_p = ws + 32 * 16384;         // 32 * 16384

    hipLaunchKernelGGL(edge_kernel, dim3(16, 32), dim3(512), 0, stream,
                       E, na, nb, W1e, b1e, W2e, b2e, el_out, suma_p, sumb_p);
    hipLaunchKernelGGL(node_kernel, dim3(256), dim3(256), 0, stream,
                       na, nb, suma_p, sumb_p, W1n, b1n, W2n, b2n, out_a, out_b);
}